// Round 3
// baseline (185.312 us; speedup 1.0000x reference)
//
#include <hip/hip_runtime.h>
#include <hip/hip_bf16.h>
#include <math.h>

#define DEMB 64
#define BM   64
#define KSMAX 24

using short8 = __attribute__((ext_vector_type(8))) short;
using f32x4  = __attribute__((ext_vector_type(4))) float;

__device__ __forceinline__ unsigned short f2bf(float x) {
    union { float f; unsigned u; } v; v.f = x;
    unsigned r = v.u + 0x7fffu + ((v.u >> 16) & 1u);   // RNE
    return (unsigned short)(r >> 16);
}

__device__ __forceinline__ short8 cvt_bf8(float4 a0, float4 a1) {
    union { short8 s; __hip_bfloat16 h[8]; } u;
    u.h[0] = __float2bfloat16(a0.x);
    u.h[1] = __float2bfloat16(a0.y);
    u.h[2] = __float2bfloat16(a0.z);
    u.h[3] = __float2bfloat16(a0.w);
    u.h[4] = __float2bfloat16(a1.x);
    u.h[5] = __float2bfloat16(a1.y);
    u.h[6] = __float2bfloat16(a1.z);
    u.h[7] = __float2bfloat16(a1.w);
    return u.s;
}

// W [Din][64] fp32 -> Wt [64][Wstride] bf16 (transposed, K zero-padded)
__global__ __launch_bounds__(256) void prep_wt(
    const float* __restrict__ W, unsigned short* __restrict__ Wt,
    int Din, int Wstride)
{
    __shared__ unsigned short tile[64][65];
    const int k0 = blockIdx.x * 64;
    const int tid = threadIdx.x;
    #pragma unroll
    for (int i = 0; i < 16; ++i) {
        int kk = i * 4 + (tid >> 6);
        int c  = tid & 63;
        int k  = k0 + kk;
        float x = (k < Din) ? W[(size_t)k * DEMB + c] : 0.f;
        tile[kk][c] = f2bf(x);
    }
    __syncthreads();
    #pragma unroll
    for (int i = 0; i < 16; ++i) {
        int c  = i * 4 + (tid >> 6);
        int kk = tid & 63;
        Wt[(size_t)c * Wstride + k0 + kk] = tile[kk][c];
    }
}

// Streaming MFMA GEMM, no LDS, no barriers.
// Each wave: 16 rows of X. A-frag loaded directly from global fp32 ->
// cvt_pk -> bf16; B-frag (bf16, L2-resident) loaded directly.
__global__ __launch_bounds__(256, 4) void gemm_stream(
    const float* __restrict__ Xq, const float* __restrict__ Xs,
    const unsigned short* __restrict__ Wt,
    float* __restrict__ qpart, float* __restrict__ spart,
    int Q, int S, int Din, int Wstride, int nQb, int cpk, int nchunk)
{
    const int tid  = threadIdx.x;
    const int wave = tid >> 6;
    const int lane = tid & 63;
    const int kg   = blockIdx.y;

    const bool isS = (int)blockIdx.x >= nQb;
    const float* X = isS ? Xs : Xq;
    const int nrows = isS ? S : Q;
    const int r0 = (isS ? (int)blockIdx.x - nQb : (int)blockIdx.x) * BM;
    float* part = isS ? spart : qpart;
    const int prow = isS ? 128 : Q;

    // A fragment coords: row = r0+16*wave+(lane&15), k-offset fk=(lane>>4)*8
    int arow = r0 + 16 * wave + (lane & 15);
    if (arow >= nrows) arow = nrows - 1;          // clamp: junk acc, never stored
    const int fk = (lane >> 4) * 8;
    const float* aptr = X + (size_t)arow * Din + fk;
    const unsigned short* bptr = Wt + (size_t)(lane & 15) * Wstride + fk;

    f32x4 acc[4] = { {0.f,0.f,0.f,0.f}, {0.f,0.f,0.f,0.f},
                     {0.f,0.f,0.f,0.f}, {0.f,0.f,0.f,0.f} };

    const int c0    = kg * cpk;
    const int c1    = (c0 + cpk < nchunk) ? c0 + cpk : nchunk;
    const int cfull = Din >> 5;                    // # full 32-k chunks (661)
    const int c1f   = (c1 < cfull) ? c1 : cfull;

    #pragma unroll 2
    for (int c = c0; c < c1f; ++c) {
        const int k0 = c * 32;
        float4 a0 = *reinterpret_cast<const float4*>(aptr + k0);
        float4 a1 = *reinterpret_cast<const float4*>(aptr + k0 + 4);
        short8 af = cvt_bf8(a0, a1);
        #pragma unroll
        for (int cb = 0; cb < 4; ++cb) {
            short8 bf = *reinterpret_cast<const short8*>(
                bptr + (size_t)cb * 16 * Wstride + k0);
            acc[cb] = __builtin_amdgcn_mfma_f32_16x16x32_bf16(af, bf, acc[cb], 0, 0, 0);
        }
    }

    // tail partial chunk (k0 + fk + 8 may exceed Din)
    if (c1 > c1f) {
        const int k0 = c1f * 32;
        float4 a0 = {0.f,0.f,0.f,0.f}, a1 = {0.f,0.f,0.f,0.f};
        if (k0 + fk + 8 <= Din) {
            a0 = *reinterpret_cast<const float4*>(aptr + k0);
            a1 = *reinterpret_cast<const float4*>(aptr + k0 + 4);
        }
        short8 af = cvt_bf8(a0, a1);
        #pragma unroll
        for (int cb = 0; cb < 4; ++cb) {
            short8 bf = *reinterpret_cast<const short8*>(
                bptr + (size_t)cb * 16 * Wstride + k0);
            acc[cb] = __builtin_amdgcn_mfma_f32_16x16x32_bf16(af, bf, acc[cb], 0, 0, 0);
        }
    }

    // epilogue: C layout col=lane&15, row=(lane>>4)*4+i
    #pragma unroll
    for (int cb = 0; cb < 4; ++cb) {
        #pragma unroll
        for (int i = 0; i < 4; ++i) {
            int row = r0 + 16 * wave + (lane >> 4) * 4 + i;
            if (row < nrows)
                part[((size_t)kg * prow + row) * DEMB + 16 * cb + (lane & 15)] = acc[cb][i];
        }
    }
}

// Reduce support partials + bias, L2-normalize -> sn [S][64]
__global__ void support_finalize(const float* __restrict__ spart,
                                 const float* __restrict__ bias,
                                 float* __restrict__ sn, int S, int nkg)
{
    int s = blockIdx.x;
    int c = threadIdx.x;  // 64
    float e = bias[c];
    for (int g = 0; g < nkg; ++g)
        e += spart[((size_t)g * 128 + s) * DEMB + c];
    float ss = e * e;
    #pragma unroll
    for (int o = 32; o >= 1; o >>= 1) ss += __shfl_xor(ss, o, 64);
    sn[(size_t)s * DEMB + c] = e / fmaxf(sqrtf(ss), 1e-8f);
}

// Fused: query reduce+bias+normalize, cosine sims, softmax, one-hot bins.
__global__ __launch_bounds__(256) void attend(
    const float* __restrict__ qpart, const float* __restrict__ sn_g,
    const float* __restrict__ bias, const int* __restrict__ labels,
    const int* __restrict__ p_nway, float* __restrict__ out,
    int S, int Q, int nkg)
{
    __shared__ float sn[100][65];
    __shared__ float qn[4][64];
    __shared__ float bins[4][32];
    __shared__ int   lab[100];

    const int tid  = threadIdx.x;
    const int w    = tid >> 6;
    const int lane = tid & 63;
    const int nw   = *p_nway;

    for (int i = tid; i < S * DEMB; i += 256) sn[i >> 6][i & 63] = sn_g[i];
    if (tid < S) lab[tid] = labels[tid];

    const int q = blockIdx.x * 4 + w;

    float e = bias[lane];
    for (int g = 0; g < nkg; ++g)
        e += qpart[((size_t)g * Q + q) * DEMB + lane];
    float ss = e * e;
    #pragma unroll
    for (int o = 32; o >= 1; o >>= 1) ss += __shfl_xor(ss, o, 64);
    e /= fmaxf(sqrtf(ss), 1e-8f);
    qn[w][lane] = e;
    if (lane < 32) bins[w][lane] = 0.f;
    __syncthreads();

    const bool v1 = (lane + 64) < S;
    const int  s1 = v1 ? lane + 64 : 0;
    float sim0 = 0.f, sim1 = 0.f;
    #pragma unroll 8
    for (int c = 0; c < DEMB; ++c) {
        float qc = qn[w][c];
        sim0 += qc * sn[lane][c];
        sim1 += qc * sn[s1][c];
    }
    if (!v1) sim1 = -INFINITY;

    float lm = fmaxf(sim0, sim1);
    #pragma unroll
    for (int o = 32; o >= 1; o >>= 1) lm = fmaxf(lm, __shfl_xor(lm, o, 64));
    float e0 = __expf(sim0 - lm);
    float e1 = v1 ? __expf(sim1 - lm) : 0.f;
    float d = e0 + e1;
    #pragma unroll
    for (int o = 32; o >= 1; o >>= 1) d += __shfl_xor(d, o, 64);

    atomicAdd(&bins[w][lab[lane]], e0);
    if (v1) atomicAdd(&bins[w][lab[s1]], e1);
    __syncthreads();

    if (lane < nw) out[(size_t)q * nw + lane] = bins[w][lane] / d;
}

extern "C" void kernel_launch(void* const* d_in, const int* in_sizes, int n_in,
                              void* d_out, int out_size, void* d_ws, size_t ws_size,
                              hipStream_t stream)
{
    const float* sup    = (const float*)d_in[0];
    const int*   labels = (const int*)d_in[1];
    const float* qry    = (const float*)d_in[2];
    const int*   p_nway = (const int*)d_in[3];
    const float* W      = (const float*)d_in[5];
    const float* bias   = (const float*)d_in[6];
    float* out = (float*)d_out;

    const int D   = DEMB;                 // 64
    const int Din = in_sizes[5] / D;      // 21168
    const int Q   = in_sizes[2] / Din;    // 4096
    const int S   = in_sizes[1];          // 100

    const int nchunk  = (Din + 31) / 32;  // 662
    const int Wstride = nchunk * 32;      // 21184

    // workspace layout
    char* wsb = (char*)d_ws;
    size_t wt_bytes = (size_t)64 * Wstride * sizeof(unsigned short); // 2.71 MB
    wt_bytes = (wt_bytes + 255) & ~(size_t)255;
    size_t sn_bytes = (size_t)S * D * sizeof(float);
    sn_bytes = (sn_bytes + 255) & ~(size_t)255;
    size_t per_ks = ((size_t)Q * D + 128 * D) * sizeof(float);

    size_t fixed = wt_bytes + sn_bytes;
    int ks = 1;
    if (ws_size > fixed + per_ks) {
        size_t avail = (ws_size - fixed) / per_ks;
        ks = (int)(avail < KSMAX ? avail : KSMAX);
        if (ks < 1) ks = 1;
    }
    const int cpk = (nchunk + ks - 1) / ks;       // chunks per K-group
    const int nkg = (nchunk + cpk - 1) / cpk;     // actual # groups

    unsigned short* Wt = (unsigned short*)wsb;
    float* sn    = (float*)(wsb + wt_bytes);
    float* spart = (float*)(wsb + wt_bytes + sn_bytes);
    float* qpart = spart + (size_t)nkg * 128 * D;

    hipLaunchKernelGGL(prep_wt, dim3((Din + 63) / 64), dim3(256), 0, stream,
                       W, Wt, Din, Wstride);

    const int nQb = (Q + BM - 1) / BM;          // 64
    const int nSb = (S + BM - 1) / BM;          // 2
    hipLaunchKernelGGL(gemm_stream, dim3(nQb + nSb, nkg), dim3(256), 0, stream,
                       qry, sup, Wt, qpart, spart, Q, S, Din, Wstride, nQb, cpk, nchunk);

    hipLaunchKernelGGL(support_finalize, dim3(S), dim3(64), 0, stream,
                       spart, bias, sn, S, nkg);

    hipLaunchKernelGGL(attend, dim3(Q / 4), dim3(256), 0, stream,
                       qpart, sn, bias, labels, p_nway, out, S, Q, nkg);
}

// Round 4
// 144.667 us; speedup vs baseline: 1.2809x; 1.2809x over previous
//
#include <hip/hip_runtime.h>
#include <hip/hip_bf16.h>
#include <math.h>

#define DEMB 64
#define BM   64
#define KSMAX 16
#define APAD 40   // LDS row stride in ushorts (80 B) — breaks 64/128-B bank alignment

using short8 = __attribute__((ext_vector_type(8))) short;
using u16x8  = __attribute__((ext_vector_type(8))) unsigned short;
using f32x4  = __attribute__((ext_vector_type(4))) float;

__device__ __forceinline__ unsigned short f2bf(float x) {
    union { float f; unsigned u; } v; v.f = x;
    unsigned r = v.u + 0x7fffu + ((v.u >> 16) & 1u);   // RNE
    return (unsigned short)(r >> 16);
}

__device__ __forceinline__ u16x8 cvt_bf8(float4 a0, float4 a1) {
    union { u16x8 s; __hip_bfloat16 h[8]; } u;
    u.h[0] = __float2bfloat16(a0.x);
    u.h[1] = __float2bfloat16(a0.y);
    u.h[2] = __float2bfloat16(a0.z);
    u.h[3] = __float2bfloat16(a0.w);
    u.h[4] = __float2bfloat16(a1.x);
    u.h[5] = __float2bfloat16(a1.y);
    u.h[6] = __float2bfloat16(a1.z);
    u.h[7] = __float2bfloat16(a1.w);
    return u.s;
}

// W [Din][64] fp32 -> Wt [64][Wstride] bf16 (transposed, K zero-padded)
__global__ __launch_bounds__(256) void prep_wt(
    const float* __restrict__ W, unsigned short* __restrict__ Wt,
    int Din, int Wstride)
{
    __shared__ unsigned short tile[64][65];
    const int k0 = blockIdx.x * 64;
    const int tid = threadIdx.x;
    #pragma unroll
    for (int i = 0; i < 16; ++i) {
        int kk = i * 4 + (tid >> 6);
        int c  = tid & 63;
        int k  = k0 + kk;
        float x = (k < Din) ? W[(size_t)k * DEMB + c] : 0.f;
        tile[kk][c] = f2bf(x);
    }
    __syncthreads();
    #pragma unroll
    for (int i = 0; i < 16; ++i) {
        int c  = i * 4 + (tid >> 6);
        int kk = tid & 63;
        Wt[(size_t)c * Wstride + k0 + kk] = tile[kk][c];
    }
}

// MFMA GEMM, reg-staged double-buffered LDS, raw s_barrier (no vmcnt drain):
// loads for chunk t+2 stay in flight across the barrier (counted waits are
// auto-generated by the compiler from reg deps).
__global__ __launch_bounds__(256) void gemm_pipe(
    const float* __restrict__ Xq, const float* __restrict__ Xs,
    const unsigned short* __restrict__ Wt,
    float* __restrict__ qpart, float* __restrict__ spart,
    int Q, int S, int Din, int Wstride, int nQb, int cpk, int nchunk)
{
    __shared__ unsigned short As[2][BM * APAD];
    __shared__ unsigned short Ws[2][DEMB * APAD];

    const int tid  = threadIdx.x;
    const int wave = tid >> 6;
    const int lane = tid & 63;
    const int kg   = blockIdx.y;

    const bool isS = (int)blockIdx.x >= nQb;
    const float* X = isS ? Xs : Xq;
    const int nrows = isS ? S : Q;
    const int r0 = (isS ? (int)blockIdx.x - nQb : (int)blockIdx.x) * BM;
    float* part = isS ? spart : qpart;
    const int prow = isS ? 128 : Q;

    // staging maps: thread -> (row = tid>>2, k-offset = (tid&3)*8)
    const int arow = tid >> 2;
    const int ak   = (tid & 3) * 8;
    const bool aval = (r0 + arow) < nrows;
    const float* aptr = X + (size_t)(r0 + arow) * Din;
    const unsigned short* wptr = Wt + (size_t)(tid >> 2) * Wstride + (tid & 3) * 8;

    // fragment coords
    const int col16 = lane & 15;
    const int frow  = 16 * wave + col16;
    const int fk    = (lane >> 4) * 8;

    f32x4 acc[4] = { {0.f,0.f,0.f,0.f}, {0.f,0.f,0.f,0.f},
                     {0.f,0.f,0.f,0.f}, {0.f,0.f,0.f,0.f} };

    const int c0 = kg * cpk;
    int c1 = c0 + cpk; if (c1 > nchunk) c1 = nchunk;
    const int n = c1 - c0;

    float4 a0_0, a1_0; u16x8 bv_0;   // slot for even j
    float4 a0_1, a1_1; u16x8 bv_1;   // slot for odd j

#define LOADC(c, A0, A1, BV) do {                                              \
    const int k0_ = (c) * 32;                                                  \
    const bool kv_ = aval && (k0_ + ak + 8 <= Din);                            \
    A0 = kv_ ? *reinterpret_cast<const float4*>(aptr + k0_ + ak)               \
             : make_float4(0.f, 0.f, 0.f, 0.f);                                \
    A1 = kv_ ? *reinterpret_cast<const float4*>(aptr + k0_ + ak + 4)           \
             : make_float4(0.f, 0.f, 0.f, 0.f);                                \
    BV = *reinterpret_cast<const u16x8*>(wptr + k0_);                          \
} while (0)

#define WRITEB(P, A0, A1, BV) do {                                             \
    u16x8 ap_ = cvt_bf8(A0, A1);                                               \
    *reinterpret_cast<u16x8*>(&As[P][arow * APAD + ak]) = ap_;                 \
    *reinterpret_cast<u16x8*>(&Ws[P][arow * APAD + ak]) = BV;                  \
} while (0)

#define LGKM0_BARRIER() do {                                                   \
    asm volatile("s_waitcnt lgkmcnt(0)" ::: "memory");                         \
    __builtin_amdgcn_s_barrier();                                              \
    asm volatile("" ::: "memory");                                             \
} while (0)

#define COMPUTE(P) do {                                                        \
    short8 af_ = *reinterpret_cast<const short8*>(&As[P][frow * APAD + fk]);   \
    short8 b0_ = *reinterpret_cast<const short8*>(&Ws[P][( 0 + col16) * APAD + fk]); \
    short8 b1_ = *reinterpret_cast<const short8*>(&Ws[P][(16 + col16) * APAD + fk]); \
    short8 b2_ = *reinterpret_cast<const short8*>(&Ws[P][(32 + col16) * APAD + fk]); \
    short8 b3_ = *reinterpret_cast<const short8*>(&Ws[P][(48 + col16) * APAD + fk]); \
    acc[0] = __builtin_amdgcn_mfma_f32_16x16x32_bf16(af_, b0_, acc[0], 0, 0, 0); \
    acc[1] = __builtin_amdgcn_mfma_f32_16x16x32_bf16(af_, b1_, acc[1], 0, 0, 0); \
    acc[2] = __builtin_amdgcn_mfma_f32_16x16x32_bf16(af_, b2_, acc[2], 0, 0, 0); \
    acc[3] = __builtin_amdgcn_mfma_f32_16x16x32_bf16(af_, b3_, acc[3], 0, 0, 0); \
} while (0)

    // prologue: chunk c0 staged to buf0; c0+1 loads left in flight
    LOADC(c0, a0_0, a1_0, bv_0);
    WRITEB(0, a0_0, a1_0, bv_0);
    if (n > 1) LOADC(c0 + 1, a0_1, a1_1, bv_1);
    LGKM0_BARRIER();

    int j = 0;
    while (true) {
        // even j: compute buf0 (chunk c0+j)
        if (j + 2 < n) LOADC(c0 + j + 2, a0_0, a1_0, bv_0);
        COMPUTE(0);
        if (j + 1 < n) { WRITEB(1, a0_1, a1_1, bv_1); LGKM0_BARRIER(); }
        if (++j >= n) break;
        // odd j: compute buf1
        if (j + 2 < n) LOADC(c0 + j + 2, a0_1, a1_1, bv_1);
        COMPUTE(1);
        if (j + 1 < n) { WRITEB(0, a0_0, a1_0, bv_0); LGKM0_BARRIER(); }
        if (++j >= n) break;
    }

#undef LOADC
#undef WRITEB
#undef LGKM0_BARRIER
#undef COMPUTE

    // epilogue: C layout col=lane&15, row=(lane>>4)*4+i
    #pragma unroll
    for (int cb = 0; cb < 4; ++cb) {
        #pragma unroll
        for (int i = 0; i < 4; ++i) {
            int row = r0 + 16 * wave + (lane >> 4) * 4 + i;
            if (row < nrows)
                part[((size_t)kg * prow + row) * DEMB + 16 * cb + col16] = acc[cb][i];
        }
    }
}

// Reduce support partials + bias, L2-normalize -> sn [S][64]
__global__ void support_finalize(const float* __restrict__ spart,
                                 const float* __restrict__ bias,
                                 float* __restrict__ sn, int S, int nkg)
{
    int s = blockIdx.x;
    int c = threadIdx.x;  // 64
    float e = bias[c];
    for (int g = 0; g < nkg; ++g)
        e += spart[((size_t)g * 128 + s) * DEMB + c];
    float ss = e * e;
    #pragma unroll
    for (int o = 32; o >= 1; o >>= 1) ss += __shfl_xor(ss, o, 64);
    sn[(size_t)s * DEMB + c] = e / fmaxf(sqrtf(ss), 1e-8f);
}

// Fused: query reduce+bias+normalize, cosine sims, softmax, one-hot bins.
__global__ __launch_bounds__(256) void attend(
    const float* __restrict__ qpart, const float* __restrict__ sn_g,
    const float* __restrict__ bias, const int* __restrict__ labels,
    const int* __restrict__ p_nway, float* __restrict__ out,
    int S, int Q, int nkg)
{
    __shared__ float sn[100][65];
    __shared__ float qn[4][64];
    __shared__ float bins[4][32];
    __shared__ int   lab[100];

    const int tid  = threadIdx.x;
    const int w    = tid >> 6;
    const int lane = tid & 63;
    const int nw   = *p_nway;

    for (int i = tid; i < S * DEMB; i += 256) sn[i >> 6][i & 63] = sn_g[i];
    if (tid < S) lab[tid] = labels[tid];

    const int q = blockIdx.x * 4 + w;

    float e = bias[lane];
    for (int g = 0; g < nkg; ++g)
        e += qpart[((size_t)g * Q + q) * DEMB + lane];
    float ss = e * e;
    #pragma unroll
    for (int o = 32; o >= 1; o >>= 1) ss += __shfl_xor(ss, o, 64);
    e /= fmaxf(sqrtf(ss), 1e-8f);
    qn[w][lane] = e;
    if (lane < 32) bins[w][lane] = 0.f;
    __syncthreads();

    const bool v1 = (lane + 64) < S;
    const int  s1 = v1 ? lane + 64 : 0;
    float sim0 = 0.f, sim1 = 0.f;
    #pragma unroll 8
    for (int c = 0; c < DEMB; ++c) {
        float qc = qn[w][c];
        sim0 += qc * sn[lane][c];
        sim1 += qc * sn[s1][c];
    }
    if (!v1) sim1 = -INFINITY;

    float lm = fmaxf(sim0, sim1);
    #pragma unroll
    for (int o = 32; o >= 1; o >>= 1) lm = fmaxf(lm, __shfl_xor(lm, o, 64));
    float e0 = __expf(sim0 - lm);
    float e1 = v1 ? __expf(sim1 - lm) : 0.f;
    float d = e0 + e1;
    #pragma unroll
    for (int o = 32; o >= 1; o >>= 1) d += __shfl_xor(d, o, 64);

    atomicAdd(&bins[w][lab[lane]], e0);
    if (v1) atomicAdd(&bins[w][lab[s1]], e1);
    __syncthreads();

    if (lane < nw) out[(size_t)q * nw + lane] = bins[w][lane] / d;
}

extern "C" void kernel_launch(void* const* d_in, const int* in_sizes, int n_in,
                              void* d_out, int out_size, void* d_ws, size_t ws_size,
                              hipStream_t stream)
{
    const float* sup    = (const float*)d_in[0];
    const int*   labels = (const int*)d_in[1];
    const float* qry    = (const float*)d_in[2];
    const int*   p_nway = (const int*)d_in[3];
    const float* W      = (const float*)d_in[5];
    const float* bias   = (const float*)d_in[6];
    float* out = (float*)d_out;

    const int D   = DEMB;                 // 64
    const int Din = in_sizes[5] / D;      // 21168
    const int Q   = in_sizes[2] / Din;    // 4096
    const int S   = in_sizes[1];          // 100

    const int nchunk  = (Din + 31) / 32;  // 662
    const int Wstride = nchunk * 32;      // 21184

    // workspace layout
    char* wsb = (char*)d_ws;
    size_t wt_bytes = (size_t)64 * Wstride * sizeof(unsigned short); // 2.71 MB
    wt_bytes = (wt_bytes + 255) & ~(size_t)255;
    size_t sn_bytes = (size_t)S * D * sizeof(float);
    sn_bytes = (sn_bytes + 255) & ~(size_t)255;
    size_t per_ks = ((size_t)Q * D + 128 * D) * sizeof(float);

    size_t fixed = wt_bytes + sn_bytes;
    int ks = 1;
    if (ws_size > fixed + per_ks) {
        size_t avail = (ws_size - fixed) / per_ks;
        ks = (int)(avail < KSMAX ? avail : KSMAX);
        if (ks < 1) ks = 1;
    }
    const int cpk = (nchunk + ks - 1) / ks;       // chunks per K-group
    const int nkg = (nchunk + cpk - 1) / cpk;     // actual # groups

    unsigned short* Wt = (unsigned short*)wsb;
    float* sn    = (float*)(wsb + wt_bytes);
    float* spart = (float*)(wsb + wt_bytes + sn_bytes);
    float* qpart = spart + (size_t)nkg * 128 * D;

    hipLaunchKernelGGL(prep_wt, dim3((Din + 63) / 64), dim3(256), 0, stream,
                       W, Wt, Din, Wstride);

    const int nQb = (Q + BM - 1) / BM;          // 64
    const int nSb = (S + BM - 1) / BM;          // 2
    hipLaunchKernelGGL(gemm_pipe, dim3(nQb + nSb, nkg), dim3(256), 0, stream,
                       qry, sup, Wt, qpart, spart, Q, S, Din, Wstride, nQb, cpk, nchunk);

    hipLaunchKernelGGL(support_finalize, dim3(S), dim3(64), 0, stream,
                       spart, bias, sn, S, nkg);

    hipLaunchKernelGGL(attend, dim3(Q / 4), dim3(256), 0, stream,
                       qpart, sn, bias, labels, p_nway, out, S, Q, nkg);
}

// Round 5
// 136.954 us; speedup vs baseline: 1.3531x; 1.0563x over previous
//
#include <hip/hip_runtime.h>
#include <hip/hip_bf16.h>
#include <math.h>

#define DEMB 64
#define BM   64
#define KSMAX 32   // k-split groups: 66*32=2112 blocks ~= 8 blocks/CU (latency hiding)

using short8 = __attribute__((ext_vector_type(8))) short;
using u16x8  = __attribute__((ext_vector_type(8))) unsigned short;
using f32x4  = __attribute__((ext_vector_type(4))) float;

__device__ __forceinline__ unsigned short f2bf(float x) {
    union { float f; unsigned u; } v; v.f = x;
    unsigned r = v.u + 0x7fffu + ((v.u >> 16) & 1u);   // RNE
    return (unsigned short)(r >> 16);
}

// W [Din][64] fp32 -> Wt [64][Wstride] bf16 (transposed, K zero-padded)
__global__ __launch_bounds__(256) void prep_wt(
    const float* __restrict__ W, unsigned short* __restrict__ Wt,
    int Din, int Wstride)
{
    __shared__ unsigned short tile[64][65];
    const int k0 = blockIdx.x * 64;
    const int tid = threadIdx.x;
    #pragma unroll
    for (int i = 0; i < 16; ++i) {
        int kk = i * 4 + (tid >> 6);
        int c  = tid & 63;
        int k  = k0 + kk;
        float x = (k < Din) ? W[(size_t)k * DEMB + c] : 0.f;
        tile[kk][c] = f2bf(x);
    }
    __syncthreads();
    #pragma unroll
    for (int i = 0; i < 16; ++i) {
        int c  = i * 4 + (tid >> 6);
        int kk = tid & 63;
        Wt[(size_t)c * Wstride + k0 + kk] = tile[kk][c];
    }
}

// MFMA GEMM: rows of Xq (and Xs for bx>=nQb) times Wt -> K-split fp32 partials.
// Round-2 structure (depth-1 reg prefetch, double-buffered LDS, one barrier
// per 32-k chunk); occupancy doubled via KSMAX=32.
__global__ __launch_bounds__(256) void gemm_mfma(
    const float* __restrict__ Xq, const float* __restrict__ Xs,
    const unsigned short* __restrict__ Wt,
    float* __restrict__ qpart, float* __restrict__ spart,
    int Q, int S, int Din, int Wstride, int nQb, int cpk, int nchunk)
{
    __shared__ unsigned short As[2][BM * 32];
    __shared__ unsigned short Ws[2][64 * 32];

    const int tid  = threadIdx.x;
    const int wave = tid >> 6;
    const int lane = tid & 63;
    const int kg   = blockIdx.y;

    const bool isS = (int)blockIdx.x >= nQb;
    const float* X = isS ? Xs : Xq;
    const int nrows = isS ? S : Q;
    const int r0 = (isS ? ((int)blockIdx.x - nQb) : (int)blockIdx.x) * BM;
    float* part = isS ? spart : qpart;
    const int prow = isS ? 128 : Q;

    // staging maps: thread -> (row = tid>>2, k-offset = (tid&3)*8)
    const int arow = tid >> 2;
    const int ak   = (tid & 3) * 8;
    const bool aval = (r0 + arow) < nrows;
    const float* aptr = X + (size_t)(r0 + arow) * Din;
    const unsigned short* wptr = Wt + (size_t)(tid >> 2) * Wstride + (tid & 3) * 8;

    // fragment coords
    const int col16 = lane & 15;
    const int frow  = 16 * wave + col16;
    const int fk    = (lane >> 4) * 8;

    f32x4 acc[4] = { {0.f,0.f,0.f,0.f}, {0.f,0.f,0.f,0.f},
                     {0.f,0.f,0.f,0.f}, {0.f,0.f,0.f,0.f} };

    const int c0 = kg * cpk;
    int c1 = c0 + cpk; if (c1 > nchunk) c1 = nchunk;

    // prologue: stage chunk c0 into buffer 0
    {
        const int k0 = c0 * 32;
        const int kk = k0 + ak;
        float4 a0 = {}, a1 = {};
        if (aval && kk + 8 <= Din) {
            a0 = *reinterpret_cast<const float4*>(aptr + kk);
            a1 = *reinterpret_cast<const float4*>(aptr + kk + 4);
        }
        u16x8 wv = *reinterpret_cast<const u16x8*>(wptr + k0);
        u16x8 ap = { f2bf(a0.x), f2bf(a0.y), f2bf(a0.z), f2bf(a0.w),
                     f2bf(a1.x), f2bf(a1.y), f2bf(a1.z), f2bf(a1.w) };
        *reinterpret_cast<u16x8*>(&As[0][arow * 32 + ak]) = ap;
        *reinterpret_cast<u16x8*>(&Ws[0][tid * 8]) = wv;
        __syncthreads();
    }

    int cur = 0;
    for (int c = c0; c < c1; ++c) {
        const int cn = c + 1;
        const bool pf = (cn < c1);
        float4 a0 = {}, a1 = {};
        u16x8 wv = {0,0,0,0,0,0,0,0};
        if (pf) {
            const int k0 = cn * 32;
            const int kk = k0 + ak;
            if (aval && kk + 8 <= Din) {
                a0 = *reinterpret_cast<const float4*>(aptr + kk);
                a1 = *reinterpret_cast<const float4*>(aptr + kk + 4);
            }
            wv = *reinterpret_cast<const u16x8*>(wptr + k0);
        }

        short8 af = *reinterpret_cast<const short8*>(&As[cur][frow * 32 + fk]);
        #pragma unroll
        for (int cb = 0; cb < 4; ++cb) {
            short8 bf = *reinterpret_cast<const short8*>(
                &Ws[cur][(16 * cb + col16) * 32 + fk]);
            acc[cb] = __builtin_amdgcn_mfma_f32_16x16x32_bf16(af, bf, acc[cb], 0, 0, 0);
        }

        if (pf) {
            u16x8 ap = { f2bf(a0.x), f2bf(a0.y), f2bf(a0.z), f2bf(a0.w),
                         f2bf(a1.x), f2bf(a1.y), f2bf(a1.z), f2bf(a1.w) };
            *reinterpret_cast<u16x8*>(&As[cur ^ 1][arow * 32 + ak]) = ap;
            *reinterpret_cast<u16x8*>(&Ws[cur ^ 1][tid * 8]) = wv;
        }
        __syncthreads();
        cur ^= 1;
    }

    // epilogue: C layout col=lane&15, row=(lane>>4)*4+i
    #pragma unroll
    for (int cb = 0; cb < 4; ++cb) {
        #pragma unroll
        for (int i = 0; i < 4; ++i) {
            int row = r0 + 16 * wave + (lane >> 4) * 4 + i;
            if (row < nrows)
                part[((size_t)kg * prow + row) * DEMB + 16 * cb + col16] = acc[cb][i];
        }
    }
}

// Reduce support partials + bias, L2-normalize -> sn [S][64]
__global__ void support_finalize(const float* __restrict__ spart,
                                 const float* __restrict__ bias,
                                 float* __restrict__ sn, int S, int nkg)
{
    int s = blockIdx.x;
    int c = threadIdx.x;  // 64
    float e = bias[c];
    for (int g = 0; g < nkg; ++g)
        e += spart[((size_t)g * 128 + s) * DEMB + c];
    float ss = e * e;
    #pragma unroll
    for (int o = 32; o >= 1; o >>= 1) ss += __shfl_xor(ss, o, 64);
    sn[(size_t)s * DEMB + c] = e / fmaxf(sqrtf(ss), 1e-8f);
}

// Fused: query reduce+bias+normalize, cosine sims, softmax, one-hot bins.
__global__ __launch_bounds__(256) void attend(
    const float* __restrict__ qpart, const float* __restrict__ sn_g,
    const float* __restrict__ bias, const int* __restrict__ labels,
    const int* __restrict__ p_nway, float* __restrict__ out,
    int S, int Q, int nkg)
{
    __shared__ float sn[100][65];
    __shared__ float qn[4][64];
    __shared__ float bins[4][32];
    __shared__ int   lab[100];

    const int tid  = threadIdx.x;
    const int w    = tid >> 6;
    const int lane = tid & 63;
    const int nw   = *p_nway;

    for (int i = tid; i < S * DEMB; i += 256) sn[i >> 6][i & 63] = sn_g[i];
    if (tid < S) lab[tid] = labels[tid];

    const int q = blockIdx.x * 4 + w;

    float e = bias[lane];
    for (int g = 0; g < nkg; ++g)
        e += qpart[((size_t)g * Q + q) * DEMB + lane];
    float ss = e * e;
    #pragma unroll
    for (int o = 32; o >= 1; o >>= 1) ss += __shfl_xor(ss, o, 64);
    e /= fmaxf(sqrtf(ss), 1e-8f);
    qn[w][lane] = e;
    if (lane < 32) bins[w][lane] = 0.f;
    __syncthreads();

    const bool v1 = (lane + 64) < S;
    const int  s1 = v1 ? lane + 64 : 0;
    float sim0 = 0.f, sim1 = 0.f;
    #pragma unroll 8
    for (int c = 0; c < DEMB; ++c) {
        float qc = qn[w][c];
        sim0 += qc * sn[lane][c];
        sim1 += qc * sn[s1][c];
    }
    if (!v1) sim1 = -INFINITY;

    float lm = fmaxf(sim0, sim1);
    #pragma unroll
    for (int o = 32; o >= 1; o >>= 1) lm = fmaxf(lm, __shfl_xor(lm, o, 64));
    float e0 = __expf(sim0 - lm);
    float e1 = v1 ? __expf(sim1 - lm) : 0.f;
    float d = e0 + e1;
    #pragma unroll
    for (int o = 32; o >= 1; o >>= 1) d += __shfl_xor(d, o, 64);

    atomicAdd(&bins[w][lab[lane]], e0);
    if (v1) atomicAdd(&bins[w][lab[s1]], e1);
    __syncthreads();

    if (lane < nw) out[(size_t)q * nw + lane] = bins[w][lane] / d;
}

extern "C" void kernel_launch(void* const* d_in, const int* in_sizes, int n_in,
                              void* d_out, int out_size, void* d_ws, size_t ws_size,
                              hipStream_t stream)
{
    const float* sup    = (const float*)d_in[0];
    const int*   labels = (const int*)d_in[1];
    const float* qry    = (const float*)d_in[2];
    const int*   p_nway = (const int*)d_in[3];
    const float* W      = (const float*)d_in[5];
    const float* bias   = (const float*)d_in[6];
    float* out = (float*)d_out;

    const int D   = DEMB;                 // 64
    const int Din = in_sizes[5] / D;      // 21168
    const int Q   = in_sizes[2] / Din;    // 4096
    const int S   = in_sizes[1];          // 100

    const int nchunk  = (Din + 31) / 32;  // 662
    const int Wstride = nchunk * 32;      // 21184

    // workspace layout
    char* wsb = (char*)d_ws;
    size_t wt_bytes = (size_t)64 * Wstride * sizeof(unsigned short); // 2.71 MB
    wt_bytes = (wt_bytes + 255) & ~(size_t)255;
    size_t sn_bytes = (size_t)S * D * sizeof(float);
    sn_bytes = (sn_bytes + 255) & ~(size_t)255;
    size_t per_ks = ((size_t)Q * D + 128 * D) * sizeof(float);

    size_t fixed = wt_bytes + sn_bytes;
    int ks = 1;
    if (ws_size > fixed + per_ks) {
        size_t avail = (ws_size - fixed) / per_ks;
        ks = (int)(avail < KSMAX ? avail : KSMAX);
        if (ks < 1) ks = 1;
    }
    const int cpk = (nchunk + ks - 1) / ks;       // chunks per K-group
    const int nkg = (nchunk + cpk - 1) / cpk;     // actual # groups

    unsigned short* Wt = (unsigned short*)wsb;
    float* sn    = (float*)(wsb + wt_bytes);
    float* spart = (float*)(wsb + wt_bytes + sn_bytes);
    float* qpart = spart + (size_t)nkg * 128 * D;

    hipLaunchKernelGGL(prep_wt, dim3((Din + 63) / 64), dim3(256), 0, stream,
                       W, Wt, Din, Wstride);

    const int nQb = (Q + BM - 1) / BM;          // 64
    const int nSb = (S + BM - 1) / BM;          // 2
    hipLaunchKernelGGL(gemm_mfma, dim3(nQb + nSb, nkg), dim3(256), 0, stream,
                       qry, sup, Wt, qpart, spart, Q, S, Din, Wstride, nQb, cpk, nchunk);

    hipLaunchKernelGGL(support_finalize, dim3(S), dim3(64), 0, stream,
                       spart, bias, sn, S, nkg);

    hipLaunchKernelGGL(attend, dim3(Q / 4), dim3(256), 0, stream,
                       qpart, sn, bias, labels, p_nway, out, S, Q, nkg);
}